// Round 2
// baseline (183.251 us; speedup 1.0000x reference)
//
#include <hip/hip_runtime.h>

#define NSAMP 2048
#define NCONF 128
#define NMO   64
#define NE    16   // electrons per spin (matrix dim)

// One thread computes det(up)*det(dn) for one (sample, config) pair.
//
// LEFT-LOOKING Householder QR: column j is gathered from global memory only
// when processed; previously formed reflectors (pre-scaled by sqrt(2/v'v),
// stored in lower-triangular V, 136 floats) are applied to it, then its own
// reflector is formed. Peak live set ~170 floats (V + one column) instead of
// the full 256-float matrix -> no spill at the 256-VGPR / 2-waves-per-SIMD
// budget. det(A) = (-1)^15 * prod(alpha_j) * R[15][15].
__global__ __launch_bounds__(256, 2)
void SlaterPooling_45543833207162_kernel(const float* __restrict__ x,
                                         const int*   __restrict__ cup,
                                         const int*   __restrict__ cdn,
                                         float*       __restrict__ out) {
  const int g = blockIdx.x * 256 + threadIdx.x;   // g in [0, 2048*128)
  const int s = g >> 7;                           // sample
  const int c = g & 127;                          // config
  const float* xs = x + (size_t)s * (2 * NE * NMO);

  float result = 1.0f;

  // spin loop NOT unrolled: V and the column regs are reused across spins
#pragma unroll 1
  for (int spin = 0; spin < 2; ++spin) {
    const int*   cfg  = (spin ? cdn : cup) + c * NE;
    const float* base = xs + spin * (NE * NMO);

    float V[NE - 1][NE];   // scaled reflector k lives in V[k][k..15]
    float det = -1.0f;     // (-1)^15 from the 15 reflectors

#pragma unroll
    for (int j = 0; j < NE; ++j) {
      // ---- lazy gather of column j ----
      const int cj = cfg[j];
      float a[NE];
#pragma unroll
      for (int i = 0; i < NE; ++i) a[i] = base[i * NMO + cj];
      // Fence: keep later columns' gathers from being hoisted above this
      // point (bounds live-load set to ~2 columns instead of 16).
      __builtin_amdgcn_sched_barrier(0);

      // ---- apply reflectors 0..j-1 (k<j folds at compile time) ----
#pragma unroll
      for (int k = 0; k < NE - 1; ++k) {
        if (k < j) {
          float w4[4] = {0.f, 0.f, 0.f, 0.f};
#pragma unroll
          for (int i = k; i < NE; ++i)
            w4[i & 3] = fmaf(V[k][i], a[i], w4[i & 3]);
          const float w = (w4[0] + w4[1]) + (w4[2] + w4[3]);
#pragma unroll
          for (int i = k; i < NE; ++i)
            a[i] = fmaf(-w, V[k][i], a[i]);
        }
      }

      // ---- form reflector j (or finish det on the last column) ----
      if (j < NE - 1) {
        float s4[4] = {0.f, 0.f, 0.f, 0.f};
#pragma unroll
        for (int i = j; i < NE; ++i)
          s4[i & 3] = fmaf(a[i], a[i], s4[i & 3]);
        const float s2    = (s4[0] + s4[1]) + (s4[2] + s4[3]);
        const float nrm   = __builtin_amdgcn_sqrtf(s2);
        const float ajj   = a[j];
        const float alpha = (ajj >= 0.0f) ? -nrm : nrm;     // R_jj
        const float vk    = ajj - alpha;                    // no cancellation
        const float vtv   = 2.0f * fmaf(-alpha, ajj, s2);   // v^T v
        // pre-scale v by sqrt(2/v'v): H = I - v''v''^T, no tau needed later
        const float scale = 1.41421356237f * __builtin_amdgcn_rsqf(vtv);
        det *= alpha;
        V[j][j] = vk * scale;
#pragma unroll
        for (int i = j + 1; i < NE; ++i) V[j][i] = a[i] * scale;
      } else {
        det *= a[NE - 1];   // R[15][15]
      }
    }
    result *= det;
  }

  out[g] = result;   // out[s*128 + c]
}

extern "C" void kernel_launch(void* const* d_in, const int* in_sizes, int n_in,
                              void* d_out, int out_size, void* d_ws, size_t ws_size,
                              hipStream_t stream) {
  const float* x   = (const float*)d_in[0];
  const int*   cup = (const int*)d_in[1];
  const int*   cdn = (const int*)d_in[2];
  float*       out = (float*)d_out;

  const int total = NSAMP * NCONF;   // 262144 threads, 1 det-pair each
  dim3 grid(total / 256), block(256);
  hipLaunchKernelGGL(SlaterPooling_45543833207162_kernel, grid, block, 0, stream,
                     x, cup, cdn, out);
}

// Round 3
// 58.055 us; speedup vs baseline: 3.1565x; 3.1565x over previous
//
#include <hip/hip_runtime.h>

#define NSAMP 2048
#define NCONF 128
#define NMO   64
#define NE    16   // electrons per spin (matrix dim)

// Block = 256 threads = 2 samples x 128 configs. The 2 samples' full MO block
// (2 x 32 x 64 floats = 16 KB) is staged coalesced into LDS once; each thread
// then gathers its 16x16 matrices from LDS (ds_read_b32, ~2-way bank alias).
//
// Per thread: det(up)*det(dn) via LEFT-LOOKING Householder QR -- column j is
// read from LDS only when processed; scaled reflectors V (lower-triangular,
// 136 floats) stay in registers. Peak live ~180 floats -> fits (256,1)
// without scratch. det(A) = (-1)^15 * prod(alpha_j) * R[15][15].
__global__ __launch_bounds__(256, 1)
void SlaterPooling_45543833207162_kernel(const float* __restrict__ x,
                                         const int*   __restrict__ cup,
                                         const int*   __restrict__ cdn,
                                         float*       __restrict__ out) {
  __shared__ float tile[2 * 2 * NE * NMO];   // [s_local][32 rows][64 cols]

  // ---- coalesced stage: 16 KB per block, 4 x float4 per thread ----
  {
    const float4* src = reinterpret_cast<const float4*>(
        x + (size_t)blockIdx.x * 2 * (2 * NE * NMO));
    float4* dst = reinterpret_cast<float4*>(tile);
#pragma unroll
    for (int k = 0; k < 4; ++k)
      dst[threadIdx.x + k * 256] = src[threadIdx.x + k * 256];
  }
  __syncthreads();

  const int s_local = threadIdx.x >> 7;        // 0..1
  const int c       = threadIdx.x & 127;       // config index (shared by all samples)
  const float* sbase = tile + s_local * (2 * NE * NMO);

  float result = 1.0f;

  // spin loop NOT unrolled: V and column regs reused across spins
#pragma unroll 1
  for (int spin = 0; spin < 2; ++spin) {
    const int*   cfg  = (spin ? cdn : cup) + c * NE;
    const float* base = sbase + spin * (NE * NMO);

    float V[NE - 1][NE];   // scaled reflector k in V[k][k..15]
    float det = -1.0f;     // (-1)^15 from 15 reflectors

#pragma unroll
    for (int j = 0; j < NE; ++j) {
      // ---- lazy gather of column j from LDS ----
      const int cj = cfg[j];
      float a[NE];
#pragma unroll
      for (int i = 0; i < NE; ++i) a[i] = base[i * NMO + cj];

      // ---- apply reflectors 0..j-1 (k<j folds at compile time) ----
#pragma unroll
      for (int k = 0; k < NE - 1; ++k) {
        if (k < j) {
          float w4[4] = {0.f, 0.f, 0.f, 0.f};
#pragma unroll
          for (int i = k; i < NE; ++i)
            w4[i & 3] = fmaf(V[k][i], a[i], w4[i & 3]);
          const float w = (w4[0] + w4[1]) + (w4[2] + w4[3]);
#pragma unroll
          for (int i = k; i < NE; ++i)
            a[i] = fmaf(-w, V[k][i], a[i]);
        }
      }

      // ---- form reflector j (or finish det on last column) ----
      if (j < NE - 1) {
        float s4[4] = {0.f, 0.f, 0.f, 0.f};
#pragma unroll
        for (int i = j; i < NE; ++i)
          s4[i & 3] = fmaf(a[i], a[i], s4[i & 3]);
        const float s2    = (s4[0] + s4[1]) + (s4[2] + s4[3]);
        const float nrm   = __builtin_amdgcn_sqrtf(s2);
        const float ajj   = a[j];
        const float alpha = (ajj >= 0.0f) ? -nrm : nrm;     // R_jj
        const float vk    = ajj - alpha;                    // no cancellation
        const float vtv   = 2.0f * fmaf(-alpha, ajj, s2);   // v^T v
        // pre-scale v by sqrt(2/v'v): H = I - v v^T, no tau needed later
        const float scale = 1.41421356237f * __builtin_amdgcn_rsqf(vtv);
        det *= alpha;
        V[j][j] = vk * scale;
#pragma unroll
        for (int i = j + 1; i < NE; ++i) V[j][i] = a[i] * scale;
      } else {
        det *= a[NE - 1];   // R[15][15]
      }
    }
    result *= det;
  }

  // out[s*128 + c]
  out[(blockIdx.x * 2 + s_local) * NCONF + c] = result;
}

extern "C" void kernel_launch(void* const* d_in, const int* in_sizes, int n_in,
                              void* d_out, int out_size, void* d_ws, size_t ws_size,
                              hipStream_t stream) {
  const float* x   = (const float*)d_in[0];
  const int*   cup = (const int*)d_in[1];
  const int*   cdn = (const int*)d_in[2];
  float*       out = (float*)d_out;

  dim3 grid(NSAMP / 2), block(256);   // 1024 blocks, 2 samples each
  hipLaunchKernelGGL(SlaterPooling_45543833207162_kernel, grid, block, 0, stream,
                     x, cup, cdn, out);
}